// Round 2
// baseline (105.904 us; speedup 1.0000x reference)
//
#include <hip/hip_runtime.h>
#include <math.h>

#define B_ 8
#define N_ 2048
#define H_ 256

// Kernel A: s[m] = sum_o w2[o] * silu( dot(h[m,:], W1[o,:]) + b1[o] ), all f64.
// Block = 256 threads (4 waves). Block covers 32 rows; wave covers 8 rows;
// lane owns 4 consecutive o's. h tile staged in LDS as f64 (broadcast reads).
__global__ __launch_bounds__(256, 2)
void s_kernel(const float* __restrict__ hp, const float* __restrict__ W1,
              const float* __restrict__ b1, const float* __restrict__ w2,
              double* __restrict__ s_out) {
    __shared__ double hs[32][H_];   // 64 KB
    const int t = threadIdx.x;
    const int m0 = blockIdx.x * 32;

    // Stage 32 rows of h into LDS as f64 (coalesced f32 loads).
    #pragma unroll
    for (int i = 0; i < 32; ++i) {
        hs[i][t] = (double)hp[(size_t)(m0 + i) * H_ + t];
    }
    __syncthreads();

    const int lane = t & 63;
    const int wave = t >> 6;
    const int r0 = wave * 8;    // rows r0..r0+7 of the tile
    const int ob = lane * 4;    // this lane's 4 output columns

    double acc[4][8];
    #pragma unroll
    for (int j = 0; j < 4; ++j)
        #pragma unroll
        for (int r = 0; r < 8; ++r) acc[j][r] = 0.0;

    for (int kc = 0; kc < H_; kc += 8) {
        // Load W1 chunk for this lane's 4 o-rows: 4 x 8 f32.
        float wreg[4][8];
        #pragma unroll
        for (int j = 0; j < 4; ++j) {
            const float* p = W1 + (size_t)(ob + j) * H_ + kc;
            float4 a = *reinterpret_cast<const float4*>(p);
            float4 b = *reinterpret_cast<const float4*>(p + 4);
            wreg[j][0] = a.x; wreg[j][1] = a.y; wreg[j][2] = a.z; wreg[j][3] = a.w;
            wreg[j][4] = b.x; wreg[j][5] = b.y; wreg[j][6] = b.z; wreg[j][7] = b.w;
        }
        #pragma unroll
        for (int kk = 0; kk < 8; ++kk) {
            double hv[8];
            #pragma unroll
            for (int r = 0; r < 8; ++r) hv[r] = hs[r0 + r][kc + kk];  // broadcast
            #pragma unroll
            for (int j = 0; j < 4; ++j) {
                const double w = (double)wreg[j][kk];
                #pragma unroll
                for (int r = 0; r < 8; ++r) acc[j][r] = fma(w, hv[r], acc[j][r]);
            }
        }
    }

    // Epilogue: bias + silu + dot with w2 (per-lane partial over its 4 o's).
    double spart[8];
    #pragma unroll
    for (int r = 0; r < 8; ++r) spart[r] = 0.0;
    #pragma unroll
    for (int j = 0; j < 4; ++j) {
        const int o = ob + j;
        const double bb = (double)b1[o];
        const double ww = (double)w2[o];
        #pragma unroll
        for (int r = 0; r < 8; ++r) {
            const double u = acc[j][r] + bb;
            const double x = u / (1.0 + exp(-u));   // silu in f64
            spart[r] += ww * x;
        }
    }

    // Wave-level reduction over the 64 lanes (all 256 o's).
    #pragma unroll
    for (int r = 0; r < 8; ++r) {
        double v = spart[r];
        for (int off = 32; off > 0; off >>= 1)
            v += __shfl_down(v, off, 64);
        if (lane == 0) s_out[m0 + r0 + r] = v;
    }
}

// Kernel B: out[b,i,j] = (int32)trunc( (s[b,i] - s[b,j]) + b2 )
// Harness reads integer-dtype outputs as int32 — store int32, not float.
__global__ __launch_bounds__(256)
void pair_kernel(const double* __restrict__ s, const float* __restrict__ b2p,
                 int* __restrict__ out) {
    const double b2 = (double)b2p[0];
    const unsigned total4 = (unsigned)(B_) * (unsigned)(N_) * (unsigned)(N_) / 4u;
    const unsigned stride = gridDim.x * blockDim.x;
    for (unsigned idx = blockIdx.x * blockDim.x + threadIdx.x; idx < total4;
         idx += stride) {
        const unsigned base = idx * 4u;                 // element index, %4==0
        const unsigned bi  = base >> 22;                // / (N*N), N*N = 2^22
        const unsigned rem = base & ((1u << 22) - 1u);
        const unsigned i   = rem >> 11;                 // / N
        const unsigned j   = rem & (N_ - 1u);
        const double si = s[bi * N_ + i];
        const double* sp = s + bi * N_ + j;             // 32B aligned (j%4==0)
        const double sj0 = sp[0], sj1 = sp[1], sj2 = sp[2], sj3 = sp[3];
        int4 o;
        o.x = (int)trunc((si - sj0) + b2);
        o.y = (int)trunc((si - sj1) + b2);
        o.z = (int)trunc((si - sj2) + b2);
        o.w = (int)trunc((si - sj3) + b2);
        *reinterpret_cast<int4*>(out + base) = o;
    }
}

extern "C" void kernel_launch(void* const* d_in, const int* in_sizes, int n_in,
                              void* d_out, int out_size, void* d_ws, size_t ws_size,
                              hipStream_t stream) {
    const float* hp = (const float*)d_in[0];
    // d_in[1] = node_mask (unused by the reference math)
    // d_in[2] = n_nodes   (unused)
    const float* W1 = (const float*)d_in[3];
    const float* b1 = (const float*)d_in[4];
    const float* w2 = (const float*)d_in[5];
    const float* b2 = (const float*)d_in[6];
    double* s  = (double*)d_ws;          // 16384 doubles = 128 KB scratch
    int* out = (int*)d_out;

    s_kernel<<<(B_ * N_) / 32, 256, 0, stream>>>(hp, W1, b1, w2, s);
    pair_kernel<<<2048, 256, 0, stream>>>(s, b2, out);
}